// Round 3
// baseline (124.674 us; speedup 1.0000x reference)
//
#include <hip/hip_runtime.h>
#include <math.h>

// Problem constants: b=64, seq=2048, hid=256
#define BATCH 64
#define SEQ   2048
#define HID   256
#define KNEG  63            // b - 1

// loss denominator: b*200*(K+1)*4 = 3,276,800
#define INV_DENOM (1.0f / 3276800.0f)

__device__ __forceinline__ float dot4(const float4& u, const float4& v) {
  return u.x * v.x + u.y * v.y + u.z * v.z + u.w * v.w;
}
__device__ __forceinline__ void fma4(float4& acc, const float4& v, float s) {
  acc.x = fmaf(v.x, s, acc.x);
  acc.y = fmaf(v.y, s, acc.y);
  acc.z = fmaf(v.z, s, acc.z);
  acc.w = fmaf(v.w, s, acc.w);
}

// Block s computes (math identical to R1, verified absmax 0.0):
//   D[s] = sum_i <rs_n[i,s], rt_n[i,s]>,  S[s] = sum_i rs_n[i,s,:],
//   T[s] = sum_i rt_n[i,s,:]
//   partial[s] = (2*b - (1.5 + 1/(2K))*D + <S,T>/(2K)) * INV_DENOM
// Last block to finish reduces partial[] -> out (fixed-order, deterministic).
//
// Layout (R3): each wave splits 32/32; half h handles row i = wave*16+2r+h.
// Lane j (0..31) covers hid elements {j*4..j*4+3} and {128+j*4..+3} —
// each half-wave load is a contiguous 512B segment. Row reduction is a
// 5-step butterfly (xor 1..16 stays inside the 32-lane half).
// VGPR discipline: __launch_bounds__(256,8) pins 8 waves/EU (<=64 VGPR).
// R2 lesson: 80 VGPR halved occupancy and doubled runtime.
__global__ __launch_bounds__(256, 8) void cosnce_fused(
    const float* __restrict__ rs, const float* __restrict__ rt,
    float* __restrict__ partial, unsigned int* __restrict__ counter,
    float* __restrict__ out) {
  const int s    = blockIdx.x;      // 0..SEQ-1
  const int tid  = threadIdx.x;     // 0..255
  const int wave = tid >> 6;        // 0..3
  const int lane = tid & 63;        // 0..63
  const int h    = lane >> 5;       // half-wave index 0/1
  const int j    = lane & 31;       // lane within half

  float4 Sacc0 = make_float4(0.f, 0.f, 0.f, 0.f);
  float4 Sacc1 = Sacc0, Tacc0 = Sacc0, Tacc1 = Sacc0;
  float  Dacc  = 0.f;

#pragma unroll 2
  for (int r = 0; r < 8; ++r) {
    const int    i    = wave * 16 + r * 2 + h;
    const size_t base = ((size_t)i * SEQ + s) * HID + j * 4;
    const float4 a0 = *(const float4*)(rs + base);
    const float4 a1 = *(const float4*)(rs + base + 128);
    const float4 b0 = *(const float4*)(rt + base);
    const float4 b1 = *(const float4*)(rt + base + 128);

    float ss = dot4(a0, a0) + dot4(a1, a1);
    float tt = dot4(b0, b0) + dot4(b1, b1);
    float st = dot4(a0, b0) + dot4(a1, b1);

    // 5-step butterfly within the 32-lane half (xor<=16 stays in-half)
#pragma unroll
    for (int off = 1; off <= 16; off <<= 1) {
      ss += __shfl_xor(ss, off);
      tt += __shfl_xor(tt, off);
      st += __shfl_xor(st, off);
    }

    // F.normalize: x / max(||x||, 1e-12)  ->  rsq(max(ss, 1e-24))
    const float inv_s = __builtin_amdgcn_rsqf(fmaxf(ss, 1e-24f));
    const float inv_t = __builtin_amdgcn_rsqf(fmaxf(tt, 1e-24f));

    Dacc = fmaf(st, inv_s * inv_t, Dacc);
    fma4(Sacc0, a0, inv_s); fma4(Sacc1, a1, inv_s);
    fma4(Tacc0, b0, inv_t); fma4(Tacc1, b1, inv_t);
  }

  // Combine the two halves: lane j and lane j+32 hold the same hid elements
  // (for different row sets) -> one xor-32 step. 17 shuffles, once per kernel.
  Sacc0.x += __shfl_xor(Sacc0.x, 32); Sacc0.y += __shfl_xor(Sacc0.y, 32);
  Sacc0.z += __shfl_xor(Sacc0.z, 32); Sacc0.w += __shfl_xor(Sacc0.w, 32);
  Sacc1.x += __shfl_xor(Sacc1.x, 32); Sacc1.y += __shfl_xor(Sacc1.y, 32);
  Sacc1.z += __shfl_xor(Sacc1.z, 32); Sacc1.w += __shfl_xor(Sacc1.w, 32);
  Tacc0.x += __shfl_xor(Tacc0.x, 32); Tacc0.y += __shfl_xor(Tacc0.y, 32);
  Tacc0.z += __shfl_xor(Tacc0.z, 32); Tacc0.w += __shfl_xor(Tacc0.w, 32);
  Tacc1.x += __shfl_xor(Tacc1.x, 32); Tacc1.y += __shfl_xor(Tacc1.y, 32);
  Tacc1.z += __shfl_xor(Tacc1.z, 32); Tacc1.w += __shfl_xor(Tacc1.w, 32);
  Dacc    += __shfl_xor(Dacc, 32);   // all 64 lanes now hold wave-total D

  __shared__ float S_sh[4][HID];
  __shared__ float T_sh[4][HID];
  __shared__ float D_sh[4];
  __shared__ float red_sh[4];
  __shared__ unsigned int done_sh;

  if (h == 0) {
    *(float4*)&S_sh[wave][j * 4]       = Sacc0;
    *(float4*)&S_sh[wave][128 + j * 4] = Sacc1;
    *(float4*)&T_sh[wave][j * 4]       = Tacc0;
    *(float4*)&T_sh[wave][128 + j * 4] = Tacc1;
    if (j == 0) D_sh[wave] = Dacc;
  }
  __syncthreads();

  // thread t combines hid element t across the 4 waves; block-reduce <S,T>
  float Ssum = S_sh[0][tid] + S_sh[1][tid] + S_sh[2][tid] + S_sh[3][tid];
  float Tsum = T_sh[0][tid] + T_sh[1][tid] + T_sh[2][tid] + T_sh[3][tid];
  float prod = Ssum * Tsum;
#pragma unroll
  for (int off = 32; off > 0; off >>= 1) prod += __shfl_xor(prod, off);
  if (lane == 0) red_sh[wave] = prod;
  __syncthreads();

  if (tid == 0) {
    const float STdot = red_sh[0] + red_sh[1] + red_sh[2] + red_sh[3];
    const float Dtot  = D_sh[0] + D_sh[1] + D_sh[2] + D_sh[3];
    const float inv2K = 1.f / (2.f * (float)KNEG);
    const float cres  = 2.f * (float)BATCH - (1.5f + inv2K) * Dtot + STdot * inv2K;
    partial[s] = cres * INV_DENOM;
    __threadfence();                        // release partial[s]
    done_sh = atomicAdd(counter, 1u);
  }
  __syncthreads();

  // Last block to finish does the deterministic fixed-order final sum.
  if (done_sh == SEQ - 1) {
    __threadfence();                        // acquire all partial[] writes
    float acc = 0.f;
    for (int idx = tid; idx < SEQ; idx += 256) acc += partial[idx];
#pragma unroll
    for (int off = 32; off > 0; off >>= 1) acc += __shfl_xor(acc, off);
    if (lane == 0) red_sh[wave] = acc;
    __syncthreads();
    if (tid == 0) out[0] = red_sh[0] + red_sh[1] + red_sh[2] + red_sh[3];
  }
}

extern "C" void kernel_launch(void* const* d_in, const int* in_sizes, int n_in,
                              void* d_out, int out_size, void* d_ws, size_t ws_size,
                              hipStream_t stream) {
  const float* rs = (const float*)d_in[0];   // r_s [64,2048,256] fp32
  const float* rt = (const float*)d_in[1];   // r_t [64,2048,256] fp32
  float* out      = (float*)d_out;           // scalar fp32 loss
  float* partial  = (float*)d_ws;            // SEQ floats
  unsigned int* counter = (unsigned int*)((char*)d_ws + SEQ * sizeof(float));

  // counter must start at 0 every call (ws poisoned once, never re-poisoned)
  hipMemsetAsync(counter, 0, sizeof(unsigned int), stream);
  cosnce_fused<<<SEQ, 256, 0, stream>>>(rs, rt, partial, counter, out);
}

// Round 4
// 52.004 us; speedup vs baseline: 2.3974x; 2.3974x over previous
//
#include <hip/hip_runtime.h>
#include <math.h>

// Problem constants: b=64, seq=2048, hid=256
#define BATCH 64
#define SEQ   2048
#define HID   256
#define KNEG  63            // b - 1

// loss denominator: b*200*(K+1)*4 = 3,276,800
#define INV_DENOM (1.0f / 3276800.0f)

__device__ __forceinline__ float dot4(const float4& u, const float4& v) {
  return u.x * v.x + u.y * v.y + u.z * v.z + u.w * v.w;
}
__device__ __forceinline__ void fma4(float4& acc, const float4& v, float s) {
  acc.x = fmaf(v.x, s, acc.x);
  acc.y = fmaf(v.y, s, acc.y);
  acc.z = fmaf(v.z, s, acc.z);
  acc.w = fmaf(v.w, s, acc.w);
}

// Block s computes:
//   D[s] = sum_i <rs_n[i,s], rt_n[i,s]>,  S[s] = sum_i rs_n[i,s,:],
//   T[s] = sum_i rt_n[i,s,:]
//   partial[s] = (2*b - (1.5 + 1/(2K))*D + <S,T>/(2K)) * INV_DENOM
//
// R4: two-kernel structure (R1, proven 52us) + R3 inner loop (137 vs 288
// shuffles/wave). NO atomics / threadfence — R2/R3 showed the fused
// last-block reduction costs ~65us of serialized same-line atomic tail.
//
// Layout: each wave splits 32/32; half h handles row i = wave*16+2r+h.
// Lane j (0..31) covers hid elements {j*4..j*4+3} and {128+j*4..+3}.
// Row reduction = 5-step butterfly (xor 1..16 stays inside the half).
__global__ __launch_bounds__(256, 8) void cosnce_per_s(
    const float* __restrict__ rs, const float* __restrict__ rt,
    float* __restrict__ partial) {
  const int s    = blockIdx.x;      // 0..SEQ-1
  const int tid  = threadIdx.x;     // 0..255
  const int wave = tid >> 6;        // 0..3
  const int lane = tid & 63;        // 0..63
  const int h    = lane >> 5;       // half-wave index 0/1
  const int j    = lane & 31;       // lane within half

  float4 Sacc0 = make_float4(0.f, 0.f, 0.f, 0.f);
  float4 Sacc1 = Sacc0, Tacc0 = Sacc0, Tacc1 = Sacc0;
  float  Dacc  = 0.f;

#pragma unroll 2
  for (int r = 0; r < 8; ++r) {
    const int    i    = wave * 16 + r * 2 + h;
    const size_t base = ((size_t)i * SEQ + s) * HID + j * 4;
    const float4 a0 = *(const float4*)(rs + base);
    const float4 a1 = *(const float4*)(rs + base + 128);
    const float4 b0 = *(const float4*)(rt + base);
    const float4 b1 = *(const float4*)(rt + base + 128);

    float ss = dot4(a0, a0) + dot4(a1, a1);
    float tt = dot4(b0, b0) + dot4(b1, b1);
    float st = dot4(a0, b0) + dot4(a1, b1);

    // 5-step butterfly within the 32-lane half (xor<=16 stays in-half)
#pragma unroll
    for (int off = 1; off <= 16; off <<= 1) {
      ss += __shfl_xor(ss, off);
      tt += __shfl_xor(tt, off);
      st += __shfl_xor(st, off);
    }

    // F.normalize: x / max(||x||, 1e-12)  ->  rsq(max(ss, 1e-24))
    const float inv_s = __builtin_amdgcn_rsqf(fmaxf(ss, 1e-24f));
    const float inv_t = __builtin_amdgcn_rsqf(fmaxf(tt, 1e-24f));

    Dacc = fmaf(st, inv_s * inv_t, Dacc);
    fma4(Sacc0, a0, inv_s); fma4(Sacc1, a1, inv_s);
    fma4(Tacc0, b0, inv_t); fma4(Tacc1, b1, inv_t);
  }

  // Combine halves: lane j and lane j+32 hold the same hid elements
  // (different row sets) -> one xor-32 step.
  Sacc0.x += __shfl_xor(Sacc0.x, 32); Sacc0.y += __shfl_xor(Sacc0.y, 32);
  Sacc0.z += __shfl_xor(Sacc0.z, 32); Sacc0.w += __shfl_xor(Sacc0.w, 32);
  Sacc1.x += __shfl_xor(Sacc1.x, 32); Sacc1.y += __shfl_xor(Sacc1.y, 32);
  Sacc1.z += __shfl_xor(Sacc1.z, 32); Sacc1.w += __shfl_xor(Sacc1.w, 32);
  Tacc0.x += __shfl_xor(Tacc0.x, 32); Tacc0.y += __shfl_xor(Tacc0.y, 32);
  Tacc0.z += __shfl_xor(Tacc0.z, 32); Tacc0.w += __shfl_xor(Tacc0.w, 32);
  Tacc1.x += __shfl_xor(Tacc1.x, 32); Tacc1.y += __shfl_xor(Tacc1.y, 32);
  Tacc1.z += __shfl_xor(Tacc1.z, 32); Tacc1.w += __shfl_xor(Tacc1.w, 32);
  Dacc    += __shfl_xor(Dacc, 32);   // all lanes hold wave-total D

  __shared__ float S_sh[4][HID];
  __shared__ float T_sh[4][HID];
  __shared__ float D_sh[4];
  __shared__ float red_sh[4];

  if (h == 0) {
    *(float4*)&S_sh[wave][j * 4]       = Sacc0;
    *(float4*)&S_sh[wave][128 + j * 4] = Sacc1;
    *(float4*)&T_sh[wave][j * 4]       = Tacc0;
    *(float4*)&T_sh[wave][128 + j * 4] = Tacc1;
    if (j == 0) D_sh[wave] = Dacc;
  }
  __syncthreads();

  // thread t combines hid element t across the 4 waves; block-reduce <S,T>
  float Ssum = S_sh[0][tid] + S_sh[1][tid] + S_sh[2][tid] + S_sh[3][tid];
  float Tsum = T_sh[0][tid] + T_sh[1][tid] + T_sh[2][tid] + T_sh[3][tid];
  float prod = Ssum * Tsum;
#pragma unroll
  for (int off = 32; off > 0; off >>= 1) prod += __shfl_xor(prod, off);
  if (lane == 0) red_sh[wave] = prod;
  __syncthreads();

  if (tid == 0) {
    const float STdot = red_sh[0] + red_sh[1] + red_sh[2] + red_sh[3];
    const float Dtot  = D_sh[0] + D_sh[1] + D_sh[2] + D_sh[3];
    const float inv2K = 1.f / (2.f * (float)KNEG);
    const float cres  = 2.f * (float)BATCH - (1.5f + inv2K) * Dtot + STdot * inv2K;
    partial[s] = cres * INV_DENOM;
  }
}

// Deterministic final reduction of SEQ partials -> scalar loss.
__global__ __launch_bounds__(256) void cosnce_reduce(
    const float* __restrict__ partial, float* __restrict__ out) {
  const int tid  = threadIdx.x;
  const int wave = tid >> 6;
  const int lane = tid & 63;
  float acc = 0.f;
  for (int idx = tid; idx < SEQ; idx += 256) acc += partial[idx];
#pragma unroll
  for (int off = 32; off > 0; off >>= 1) acc += __shfl_xor(acc, off);
  __shared__ float sh[4];
  if (lane == 0) sh[wave] = acc;
  __syncthreads();
  if (tid == 0) out[0] = sh[0] + sh[1] + sh[2] + sh[3];
}

extern "C" void kernel_launch(void* const* d_in, const int* in_sizes, int n_in,
                              void* d_out, int out_size, void* d_ws, size_t ws_size,
                              hipStream_t stream) {
  const float* rs = (const float*)d_in[0];   // r_s [64,2048,256] fp32
  const float* rt = (const float*)d_in[1];   // r_t [64,2048,256] fp32
  float* out      = (float*)d_out;           // scalar fp32 loss
  float* partial  = (float*)d_ws;            // SEQ floats of scratch

  cosnce_per_s<<<SEQ, 256, 0, stream>>>(rs, rt, partial);
  cosnce_reduce<<<1, 256, 0, stream>>>(partial, out);
}